// Round 16
// baseline (360.939 us; speedup 1.0000x reference)
//
#include <hip/hip_runtime.h>
#include <math.h>

#define NN 20000
#define MP 20096          // NN padded to multiple of 128 for MFMA GEMM A-reads
#define EE 320000
#define ET (EE + NN)
#define HC 256
#define EPS_BN 1e-5f

typedef __bf16 bf16x8 __attribute__((ext_vector_type(8)));
typedef float f32x4 __attribute__((ext_vector_type(4)));

__device__ __forceinline__ float4 ld4(const float* p) { return *reinterpret_cast<const float4*>(p); }
__device__ __forceinline__ float lrelu(float x) { return fmaxf(x, 0.f) + 0.2f * fminf(x, 0.f); }

// fp32 -> bf16 (RNE), raw ushort storage
__device__ __forceinline__ unsigned short f2b(float f) {
  unsigned int u = __float_as_uint(f);
  u = (u + 0x7fffu + ((u >> 16) & 1u)) >> 16;
  return (unsigned short)u;
}
__device__ __forceinline__ float b2f(unsigned short u) {
  return __uint_as_float(((unsigned int)u) << 16);
}

// async global->LDS, 16B per lane; LDS dest = wave-uniform base + lane*16
__device__ __forceinline__ void gld_lds16(const void* g, void* l) {
  __builtin_amdgcn_global_load_lds(
      (const __attribute__((address_space(1))) unsigned int*)g,
      (__attribute__((address_space(3))) unsigned int*)(unsigned int)(unsigned long long)l,
      16, 0, 0);
}

// ---------------- fused prep: convert_x | convert_w0 | convert_w1 ----------------
// (hist moved into csr_scan_kernel's LDS histogram)
#define CXB 5000                  // NN*512/8/256 (8 floats per thread)
#define W0B 1024                  // 512*512/256
#define W1B 512                   // 512*256/256

__device__ __forceinline__ void conv_w_body(int idx, int K, const float* Wl, const float* Wr,
                                            unsigned short* Wf) {
  int n = idx / K, k = idx - n * K;
  float v = (n < 256) ? Wl[(size_t)k * 256 + n] : Wr[(size_t)k * 256 + (n - 256)];
  Wf[idx] = f2b(v);
}

__global__ __launch_bounds__(256) void prep_kernel(const float* __restrict__ x,
                                                   unsigned short* __restrict__ xb,
                                                   const float* __restrict__ Wl0,
                                                   const float* __restrict__ Wr0,
                                                   unsigned short* __restrict__ Wf0,
                                                   const float* __restrict__ Wl1,
                                                   const float* __restrict__ Wr1,
                                                   unsigned short* __restrict__ Wf1) {
  const int b = blockIdx.x;
  if (b < CXB) {
    // convert_x: NN*512 floats -> bf16, 8/thread (exactly covers 10,240,000)
    int i = (b * 256 + threadIdx.x) * 8;
    float4 v0 = ld4(&x[i]);
    float4 v1 = ld4(&x[i + 4]);
    ushort4 o0, o1;
    o0.x = f2b(v0.x); o0.y = f2b(v0.y); o0.z = f2b(v0.z); o0.w = f2b(v0.w);
    o1.x = f2b(v1.x); o1.y = f2b(v1.y); o1.z = f2b(v1.z); o1.w = f2b(v1.w);
    *reinterpret_cast<ushort4*>(&xb[i]) = o0;
    *reinterpret_cast<ushort4*>(&xb[i + 4]) = o1;
  } else if (b < CXB + W0B) {
    conv_w_body((b - CXB) * 256 + threadIdx.x, 512, Wl0, Wr0, Wf0);
  } else {
    conv_w_body((b - CXB - W0B) * 256 + threadIdx.x, 256, Wl1, Wr1, Wf1);
  }
}

// ---------------- CSR build: single-block LDS histogram + scan ----------------
// replaces memset + global-atomic hist + scan (3 dispatch-equivalents -> 1 launch)
__global__ __launch_bounds__(1024) void csr_scan_kernel(const int* __restrict__ ei,
                                                        int* __restrict__ cursor,
                                                        int* __restrict__ offsets) {
  __shared__ int cnt[NN];   // 80 KB
  __shared__ int wsum[16];
  const int tid = threadIdx.x;
  const int lane = tid & 63, wv = tid >> 6;

  for (int j = tid; j < NN; j += 1024) cnt[j] = 0;
  __syncthreads();
  // histogram over EE real edges + NN self-loops (LDS atomics)
  for (int e = tid; e < ET; e += 1024) {
    int d = (e < EE) ? ei[EE + e] : (e - EE);
    atomicAdd(&cnt[d], 1);
  }
  __syncthreads();

  const int base = tid * 20;
  int vals[20];
  int s = 0;
  if (tid < 1000) {
#pragma unroll
    for (int j = 0; j < 20; ++j) { vals[j] = cnt[base + j]; s += vals[j]; }
  }
  int ssum = s;  // inclusive wave scan
#pragma unroll
  for (int off = 1; off < 64; off <<= 1) {
    int t = __shfl_up(ssum, off);
    if (lane >= off) ssum += t;
  }
  if (lane == 63) wsum[wv] = ssum;
  __syncthreads();
  if (wv == 0) {
    int w = (lane < 16) ? wsum[lane] : 0;
#pragma unroll
    for (int off = 1; off < 16; off <<= 1) {
      int t = __shfl_up(w, off);
      if (lane >= off) w += t;
    }
    if (lane < 16) wsum[lane] = w;
  }
  __syncthreads();
  int excl = ssum - s + (wv > 0 ? wsum[wv - 1] : 0);
  if (tid < 1000) {
    int run = excl;
#pragma unroll
    for (int j = 0; j < 20; ++j) { offsets[base + j] = run; cursor[base + j] = run; run += vals[j]; }
  }
  if (tid == 1023) offsets[NN] = wsum[15];
}

__global__ __launch_bounds__(256) void scatter_kernel(const int* __restrict__ ei,
                                                      int* __restrict__ cursor,
                                                      int* __restrict__ srcs) {
  int e = blockIdx.x * blockDim.x + threadIdx.x;
  if (e >= ET) return;
  int s, d;
  if (e < EE) { s = ei[e]; d = ei[EE + e]; } else { s = d = e - EE; }
  int pos = atomicAdd(&cursor[d], 1);
  srcs[pos] = s;
}

// ---------------- bf16 MFMA GEMM (closed after R8/R12 nulls; ring-3, XCD swizzle) ----------------
__global__ __launch_bounds__(512, 6) void gemm_mfma(const unsigned short* __restrict__ A,
                                                    const unsigned short* __restrict__ Bt,
                                                    unsigned short* __restrict__ xlb,
                                                    float* __restrict__ xrf,
                                                    int M, int K) {
  __shared__ unsigned short As[3][128 * 32];  // 3 x 8 KB
  __shared__ unsigned short Bs[3][128 * 32];  // 3 x 8 KB
  const int tid = threadIdx.x;
  const int wave = tid >> 6;
  const int lane = tid & 63;
  const int am = lane & 15;
  const int aq = lane >> 4;
  const int wr = (wave >> 2) * 64;   // 0 / 64
  const int wc = (wave & 3) * 32;    // 0 / 32 / 64 / 96

  // bijective XCD swizzle (ERRATA #11 formula)
  const int nwg = gridDim.x;         // (M/128)*4
  const int orig = blockIdx.x;
  const int q = nwg >> 3, r = nwg & 7;
  const int xcd = orig & 7, ii = orig >> 3;
  const int wgid = (xcd < r ? xcd * (q + 1) : r * (q + 1) + (xcd - r) * q) + ii;
  const int row0 = (wgid >> 2) * 128;
  const int col0 = (wgid & 3) * 128;

  const int r_ = tid >> 2;           // 0..127
  const int ks = (tid & 3) * 8;
  const size_t aoff = (size_t)(row0 + r_) * K + ks;
  const size_t boff = (size_t)(col0 + r_) * K + ks;

  const int nk = K >> 5;

#define STAGE(tt, bb)                                                    \
  do {                                                                   \
    gld_lds16(A + aoff + (size_t)(tt) * 32, &As[bb][wave * 512]);        \
    gld_lds16(Bt + boff + (size_t)(tt) * 32, &Bs[bb][wave * 512]);       \
  } while (0)

  f32x4 acc[4][2] = {};

  STAGE(0, 0);
  STAGE(1, 1);

  int cur = 0;
  int sb = 2;
  for (int t = 0; t < nk; ++t) {
    if (t + 1 < nk) {
      asm volatile("s_waitcnt vmcnt(2)" ::: "memory");
    } else {
      asm volatile("s_waitcnt vmcnt(0)" ::: "memory");
    }
    __builtin_amdgcn_s_barrier();
    __builtin_amdgcn_sched_barrier(0);

    if (t + 2 < nk) STAGE(t + 2, sb);

    bf16x8 af[4], bfr[2];
#pragma unroll
    for (int i = 0; i < 4; ++i)
      af[i] = *reinterpret_cast<const bf16x8*>(&As[cur][(wr + i * 16 + am) * 32 + aq * 8]);
#pragma unroll
    for (int j = 0; j < 2; ++j)
      bfr[j] = *reinterpret_cast<const bf16x8*>(&Bs[cur][(wc + j * 16 + am) * 32 + aq * 8]);
#pragma unroll
    for (int i = 0; i < 4; ++i)
#pragma unroll
      for (int j = 0; j < 2; ++j)
        acc[i][j] = __builtin_amdgcn_mfma_f32_16x16x32_bf16(af[i], bfr[j], acc[i][j], 0, 0, 0);

    cur = (cur == 2) ? 0 : cur + 1;
    sb = (sb == 2) ? 0 : sb + 1;
  }
#undef STAGE

  // epilogue: D col = lane&15, row = (lane>>4)*4 + reg
#pragma unroll
  for (int i = 0; i < 4; ++i) {
#pragma unroll
    for (int j = 0; j < 2; ++j) {
      int gcol = col0 + wc + j * 16 + am;
#pragma unroll
      for (int rr = 0; rr < 4; ++rr) {
        int grow = row0 + wr + i * 16 + aq * 4 + rr;
        if (grow < M) {
          float v = acc[i][j][rr];
          if (gcol < 256) xlb[(size_t)grow * 256 + gcol] = f2b(v);
          else            xrf[(size_t)grow * 256 + (gcol - 256)] = v;
        }
      }
    }
  }
}

// ---------------- GATv2 layer: wave/node, no-max softmax, 4-edge unroll, BN+ELU epilogue.
// Fused-lin2 mode (Wl2 != nullptr): project z (fp32) onto Wl2/Wr2 -> xl2/xr2, SKIP hb store
// (hb's only consumer was lin2; saves 10MB store + 10MB load + one launch).
__global__ __launch_bounds__(256) void gat_layer(const unsigned short* __restrict__ xlb,
                                                 const float* __restrict__ xrf,
                                                 const float* __restrict__ att,
                                                 const float* __restrict__ bias,
                                                 const float* __restrict__ gam,
                                                 const float* __restrict__ bet,
                                                 const float* __restrict__ mean,
                                                 const float* __restrict__ var,
                                                 const int* __restrict__ offsets,
                                                 const int* __restrict__ srcs,
                                                 unsigned short* __restrict__ hb,
                                                 const float* __restrict__ Wl2,
                                                 const float* __restrict__ Wr2,
                                                 float* __restrict__ xl2,
                                                 float* __restrict__ xr2) {
  const int wave = threadIdx.x >> 6;
  const int lane = threadIdx.x & 63;
  const int node = blockIdx.x * 4 + wave;
  if (node >= NN) return;

  const float4 xr4 = ld4(&xrf[(size_t)node * HC + lane * 4]);
  const float4 a4 = ld4(&att[lane * 4]);
  const int beg = offsets[node];
  const int end = offsets[node + 1];

  float lA = 0.f, lB = 0.f;
  float4 OA = make_float4(0.f, 0.f, 0.f, 0.f);
  float4 OB = make_float4(0.f, 0.f, 0.f, 0.f);

  int i = beg;
  for (; i + 3 < end; i += 4) {
    int s0 = srcs[i], s1 = srcs[i + 1], s2 = srcs[i + 2], s3 = srcs[i + 3];
    ushort4 u0 = *reinterpret_cast<const ushort4*>(&xlb[(size_t)s0 * HC + lane * 4]);
    ushort4 u1 = *reinterpret_cast<const ushort4*>(&xlb[(size_t)s1 * HC + lane * 4]);
    ushort4 u2 = *reinterpret_cast<const ushort4*>(&xlb[(size_t)s2 * HC + lane * 4]);
    ushort4 u3 = *reinterpret_cast<const ushort4*>(&xlb[(size_t)s3 * HC + lane * 4]);
    float4 x0 = make_float4(b2f(u0.x), b2f(u0.y), b2f(u0.z), b2f(u0.w));
    float4 x1 = make_float4(b2f(u1.x), b2f(u1.y), b2f(u1.z), b2f(u1.w));
    float4 x2 = make_float4(b2f(u2.x), b2f(u2.y), b2f(u2.z), b2f(u2.w));
    float4 x3 = make_float4(b2f(u3.x), b2f(u3.y), b2f(u3.z), b2f(u3.w));
    float e0 = lrelu(x0.x + xr4.x) * a4.x + lrelu(x0.y + xr4.y) * a4.y +
               lrelu(x0.z + xr4.z) * a4.z + lrelu(x0.w + xr4.w) * a4.w;
    float e1 = lrelu(x1.x + xr4.x) * a4.x + lrelu(x1.y + xr4.y) * a4.y +
               lrelu(x1.z + xr4.z) * a4.z + lrelu(x1.w + xr4.w) * a4.w;
    float e2 = lrelu(x2.x + xr4.x) * a4.x + lrelu(x2.y + xr4.y) * a4.y +
               lrelu(x2.z + xr4.z) * a4.z + lrelu(x2.w + xr4.w) * a4.w;
    float e3 = lrelu(x3.x + xr4.x) * a4.x + lrelu(x3.y + xr4.y) * a4.y +
               lrelu(x3.z + xr4.z) * a4.z + lrelu(x3.w + xr4.w) * a4.w;
#pragma unroll
    for (int off = 1; off < 16; off <<= 1) {
      e0 += __shfl_xor(e0, off);
      e1 += __shfl_xor(e1, off);
      e2 += __shfl_xor(e2, off);
      e3 += __shfl_xor(e3, off);
    }
    float p0 = __expf(e0), p1 = __expf(e1), p2 = __expf(e2), p3 = __expf(e3);
    lA += p0; lB += p1; lA += p2; lB += p3;
    OA.x += p0 * x0.x; OA.y += p0 * x0.y; OA.z += p0 * x0.z; OA.w += p0 * x0.w;
    OB.x += p1 * x1.x; OB.y += p1 * x1.y; OB.z += p1 * x1.z; OB.w += p1 * x1.w;
    OA.x += p2 * x2.x; OA.y += p2 * x2.y; OA.z += p2 * x2.z; OA.w += p2 * x2.w;
    OB.x += p3 * x3.x; OB.y += p3 * x3.y; OB.z += p3 * x3.z; OB.w += p3 * x3.w;
  }
  for (; i < end; ++i) {
    int s = srcs[i];
    ushort4 u = *reinterpret_cast<const ushort4*>(&xlb[(size_t)s * HC + lane * 4]);
    float4 x0 = make_float4(b2f(u.x), b2f(u.y), b2f(u.z), b2f(u.w));
    float e = lrelu(x0.x + xr4.x) * a4.x + lrelu(x0.y + xr4.y) * a4.y +
              lrelu(x0.z + xr4.z) * a4.z + lrelu(x0.w + xr4.w) * a4.w;
#pragma unroll
    for (int off = 1; off < 16; off <<= 1) e += __shfl_xor(e, off);
    float p = __expf(e);
    lA += p;
    OA.x += p * x0.x; OA.y += p * x0.y; OA.z += p * x0.z; OA.w += p * x0.w;
  }
  float inv = 1.f / (lA + lB);
  float4 O = make_float4(OA.x + OB.x, OA.y + OB.y, OA.z + OB.z, OA.w + OB.w);

  float4 b4 = ld4(&bias[lane * 4]);
  float4 g4 = ld4(&gam[lane * 4]);
  float4 e4 = ld4(&bet[lane * 4]);
  float4 m4 = ld4(&mean[lane * 4]);
  float4 v4 = ld4(&var[lane * 4]);
  float y0 = O.x * inv + b4.x, y1 = O.y * inv + b4.y;
  float y2 = O.z * inv + b4.z, y3 = O.w * inv + b4.w;
  float z0 = (y0 - m4.x) * (g4.x * rsqrtf(v4.x + EPS_BN)) + e4.x;
  float z1 = (y1 - m4.y) * (g4.y * rsqrtf(v4.y + EPS_BN)) + e4.y;
  float z2 = (y2 - m4.z) * (g4.z * rsqrtf(v4.z + EPS_BN)) + e4.z;
  float z3 = (y3 - m4.w) * (g4.w * rsqrtf(v4.w + EPS_BN)) + e4.w;
  z0 = z0 > 0.f ? z0 : expm1f(z0);
  z1 = z1 > 0.f ? z1 : expm1f(z1);
  z2 = z2 > 0.f ? z2 : expm1f(z2);
  z3 = z3 > 0.f ? z3 : expm1f(z3);

  if (Wl2 != nullptr) {
    // fused lin2: h = z (fp32), project 256 -> 2 twice, wave-reduce, lane0 writes
    float zz[4] = {z0, z1, z2, z3};
    float l0 = 0.f, l1 = 0.f, r0 = 0.f, r1 = 0.f;
#pragma unroll
    for (int j = 0; j < 4; ++j) {
      int row = lane * 4 + j;
      l0 += zz[j] * Wl2[row * 2 + 0];
      l1 += zz[j] * Wl2[row * 2 + 1];
      r0 += zz[j] * Wr2[row * 2 + 0];
      r1 += zz[j] * Wr2[row * 2 + 1];
    }
#pragma unroll
    for (int off = 1; off < 64; off <<= 1) {
      l0 += __shfl_xor(l0, off);
      l1 += __shfl_xor(l1, off);
      r0 += __shfl_xor(r0, off);
      r1 += __shfl_xor(r1, off);
    }
    if (lane == 0) {
      xl2[node * 2 + 0] = l0; xl2[node * 2 + 1] = l1;
      xr2[node * 2 + 0] = r0; xr2[node * 2 + 1] = r1;
    }
  } else {
    ushort4 r;
    r.x = f2b(z0); r.y = f2b(z1); r.z = f2b(z2); r.w = f2b(z3);
    *reinterpret_cast<ushort4*>(&hb[(size_t)node * HC + lane * 4]) = r;
  }
}

// ---------------- layer 2 attention + log_softmax (wave per node, lane per edge, no-max) ----------------
__global__ __launch_bounds__(256) void gat2_out_kernel(const float* __restrict__ xl2,
                                                       const float* __restrict__ xr2,
                                                       const float* __restrict__ att2,
                                                       const float* __restrict__ b2,
                                                       const int* __restrict__ offsets,
                                                       const int* __restrict__ srcs,
                                                       float* __restrict__ out) {
  const int wave = threadIdx.x >> 6;
  const int lane = threadIdx.x & 63;
  const int node = blockIdx.x * 4 + wave;
  if (node >= NN) return;
  const float a0 = att2[0], a1 = att2[1];
  const float xr0 = xr2[node * 2 + 0], xr1 = xr2[node * 2 + 1];
  const int beg = offsets[node], end = offsets[node + 1];

  float l = 0.f, o0 = 0.f, o1 = 0.f;
  for (int i = beg + lane; i < end; i += 64) {
    int s = srcs[i];
    float x0 = xl2[s * 2 + 0], x1 = xl2[s * 2 + 1];
    float e = lrelu(x0 + xr0) * a0 + lrelu(x1 + xr1) * a1;
    float p = __expf(e);
    l += p;
    o0 += p * x0;
    o1 += p * x1;
  }
#pragma unroll
  for (int off = 1; off < 64; off <<= 1) {
    l += __shfl_xor(l, off);
    o0 += __shfl_xor(o0, off);
    o1 += __shfl_xor(o1, off);
  }
  if (lane == 0) {
    float inv = 1.f / l;
    float t0 = o0 * inv + b2[0];
    float t1 = o1 * inv + b2[1];
    float mx = fmaxf(t0, t1);
    float ls = mx + logf(__expf(t0 - mx) + __expf(t1 - mx));
    out[node * 2 + 0] = t0 - ls;
    out[node * 2 + 1] = t1 - ls;
  }
}

extern "C" void kernel_launch(void* const* d_in, const int* in_sizes, int n_in,
                              void* d_out, int out_size, void* d_ws, size_t ws_size,
                              hipStream_t stream) {
  const float* x    = (const float*)d_in[0];
  const int*   ei   = (const int*)d_in[1];
  const float* Wl0  = (const float*)d_in[2];
  const float* Wr0  = (const float*)d_in[3];
  const float* att0 = (const float*)d_in[4];
  const float* b0   = (const float*)d_in[5];
  const float* g0   = (const float*)d_in[6];
  const float* be0  = (const float*)d_in[7];
  const float* m0   = (const float*)d_in[8];
  const float* v0   = (const float*)d_in[9];
  const float* Wl1  = (const float*)d_in[10];
  const float* Wr1  = (const float*)d_in[11];
  const float* att1 = (const float*)d_in[12];
  const float* b1   = (const float*)d_in[13];
  const float* g1   = (const float*)d_in[14];
  const float* be1  = (const float*)d_in[15];
  const float* m1   = (const float*)d_in[16];
  const float* v1   = (const float*)d_in[17];
  const float* Wl2  = (const float*)d_in[18];
  const float* Wr2  = (const float*)d_in[19];
  const float* att2 = (const float*)d_in[20];
  const float* b2   = (const float*)d_in[21];

  // workspace layout (~64.2 MB)
  float* xrf = (float*)d_ws;                                   // NN*256 fp32
  unsigned short* xlb = (unsigned short*)(xrf + (size_t)NN * 256);  // NN*256 bf16
  unsigned short* hb  = xlb + (size_t)NN * 256;                // MP*256 bf16
  unsigned short* xb  = hb + (size_t)MP * 256;                 // MP*512 bf16
  unsigned short* Wf0 = xb + (size_t)MP * 512;                 // 512*512 bf16
  unsigned short* Wf1 = Wf0 + 512 * 512;                       // 512*256 bf16
  float* xl2 = (float*)(Wf1 + 512 * 256);                      // 2*NN
  float* xr2 = xl2 + 2 * NN;                                   // 2*NN
  int* offsets = (int*)(xr2 + 2 * NN);                         // NN+1
  int* cursor  = offsets + (NN + 1);                           // NN
  int* srcs    = cursor + NN;                                  // ET

  // --- prep (convert_x | convert_w0 | convert_w1) + CSR build (LDS hist+scan, scatter) ---
  prep_kernel<<<CXB + W0B + W1B, 256, 0, stream>>>(x, xb, Wl0, Wr0, Wf0, Wl1, Wr1, Wf1);
  csr_scan_kernel<<<1, 1024, 0, stream>>>(ei, cursor, offsets);
  scatter_kernel<<<(ET + 255) / 256, 256, 0, stream>>>(ei, cursor, srcs);

  const int gemm_blocks = (MP / 128) * 4;  // 628, 1D grid (swizzled in-kernel)
  // --- layer 0 ---
  gemm_mfma<<<gemm_blocks, 512, 0, stream>>>(xb, Wf0, xlb, xrf, NN, 512);
  gat_layer<<<NN / 4, 256, 0, stream>>>(xlb, xrf, att0, b0, g0, be0, m0, v0, offsets, srcs, hb,
                                        nullptr, nullptr, nullptr, nullptr);
  // --- layer 1 (lin2 fused into epilogue; hb not written) ---
  gemm_mfma<<<gemm_blocks, 512, 0, stream>>>(hb, Wf1, xlb, xrf, NN, 256);
  gat_layer<<<NN / 4, 256, 0, stream>>>(xlb, xrf, att1, b1, g1, be1, m1, v1, offsets, srcs, hb,
                                        Wl2, Wr2, xl2, xr2);
  // --- layer 2 ---
  gat2_out_kernel<<<NN / 4, 256, 0, stream>>>(xl2, xr2, att2, b2, offsets, srcs, (float*)d_out);
}

// Round 18
// 280.298 us; speedup vs baseline: 1.2877x; 1.2877x over previous
//
#include <hip/hip_runtime.h>
#include <math.h>

#define NN 20000
#define MP 20096          // NN padded to multiple of 128 for MFMA GEMM A-reads
#define EE 320000
#define ET (EE + NN)
#define HC 256
#define EPS_BN 1e-5f

typedef __bf16 bf16x8 __attribute__((ext_vector_type(8)));
typedef float f32x4 __attribute__((ext_vector_type(4)));

__device__ __forceinline__ float4 ld4(const float* p) { return *reinterpret_cast<const float4*>(p); }
__device__ __forceinline__ float lrelu(float x) { return fmaxf(x, 0.f) + 0.2f * fminf(x, 0.f); }

// fp32 -> bf16 (RNE), raw ushort storage
__device__ __forceinline__ unsigned short f2b(float f) {
  unsigned int u = __float_as_uint(f);
  u = (u + 0x7fffu + ((u >> 16) & 1u)) >> 16;
  return (unsigned short)u;
}
__device__ __forceinline__ float b2f(unsigned short u) {
  return __uint_as_float(((unsigned int)u) << 16);
}

// async global->LDS, 16B per lane; LDS dest = wave-uniform base + lane*16
__device__ __forceinline__ void gld_lds16(const void* g, void* l) {
  __builtin_amdgcn_global_load_lds(
      (const __attribute__((address_space(1))) unsigned int*)g,
      (__attribute__((address_space(3))) unsigned int*)(unsigned int)(unsigned long long)l,
      16, 0, 0);
}

// ---------------- fused prep: convert_x | hist | convert_w0 | convert_w1 ----------------
// (R16 lesson: hist must stay massively parallel — single-block LDS hist was 120-160us)
#define CXB 5000                  // NN*512/8/256 (8 floats per thread)
#define HB  ((ET + 255) / 256)    // 1329
#define W0B 1024                  // 512*512/256
#define W1B 512                   // 512*256/256

__device__ __forceinline__ void conv_w_body(int idx, int K, const float* Wl, const float* Wr,
                                            unsigned short* Wf) {
  int n = idx / K, k = idx - n * K;
  float v = (n < 256) ? Wl[(size_t)k * 256 + n] : Wr[(size_t)k * 256 + (n - 256)];
  Wf[idx] = f2b(v);
}

__global__ __launch_bounds__(256) void prep_kernel(const float* __restrict__ x,
                                                   unsigned short* __restrict__ xb,
                                                   const int* __restrict__ ei,
                                                   int* __restrict__ counts,
                                                   const float* __restrict__ Wl0,
                                                   const float* __restrict__ Wr0,
                                                   unsigned short* __restrict__ Wf0,
                                                   const float* __restrict__ Wl1,
                                                   const float* __restrict__ Wr1,
                                                   unsigned short* __restrict__ Wf1) {
  const int b = blockIdx.x;
  if (b < CXB) {
    // convert_x: NN*512 floats -> bf16, 8/thread (exactly covers 10,240,000)
    int i = (b * 256 + threadIdx.x) * 8;
    float4 v0 = ld4(&x[i]);
    float4 v1 = ld4(&x[i + 4]);
    ushort4 o0, o1;
    o0.x = f2b(v0.x); o0.y = f2b(v0.y); o0.z = f2b(v0.z); o0.w = f2b(v0.w);
    o1.x = f2b(v1.x); o1.y = f2b(v1.y); o1.z = f2b(v1.z); o1.w = f2b(v1.w);
    *reinterpret_cast<ushort4*>(&xb[i]) = o0;
    *reinterpret_cast<ushort4*>(&xb[i + 4]) = o1;
  } else if (b < CXB + HB) {
    int e = (b - CXB) * 256 + threadIdx.x;
    if (e < ET) {
      int d = (e < EE) ? ei[EE + e] : (e - EE);
      atomicAdd(&counts[d], 1);
    }
  } else if (b < CXB + HB + W0B) {
    conv_w_body((b - CXB - HB) * 256 + threadIdx.x, 512, Wl0, Wr0, Wf0);
  } else {
    conv_w_body((b - CXB - HB - W0B) * 256 + threadIdx.x, 256, Wl1, Wr1, Wf1);
  }
}

// ---------------- CSR build: scan + scatter ----------------
// single-block scan: 1024 threads x 20 ints each, shfl-based, 2 barriers
__global__ __launch_bounds__(1024) void scan_kernel(int* __restrict__ cursor,
                                                    int* __restrict__ offsets) {
  __shared__ int wsum[16];
  const int tid = threadIdx.x;
  const int lane = tid & 63, wv = tid >> 6;
  const int base = tid * 20;
  int vals[20];
  int s = 0;
  if (tid < 1000) {
#pragma unroll
    for (int j = 0; j < 20; ++j) { vals[j] = cursor[base + j]; s += vals[j]; }
  }
  int ssum = s;  // inclusive wave scan
#pragma unroll
  for (int off = 1; off < 64; off <<= 1) {
    int t = __shfl_up(ssum, off);
    if (lane >= off) ssum += t;
  }
  if (lane == 63) wsum[wv] = ssum;
  __syncthreads();
  if (wv == 0) {
    int w = (lane < 16) ? wsum[lane] : 0;
#pragma unroll
    for (int off = 1; off < 16; off <<= 1) {
      int t = __shfl_up(w, off);
      if (lane >= off) w += t;
    }
    if (lane < 16) wsum[lane] = w;
  }
  __syncthreads();
  int excl = ssum - s + (wv > 0 ? wsum[wv - 1] : 0);
  if (tid < 1000) {
    int run = excl;
#pragma unroll
    for (int j = 0; j < 20; ++j) { offsets[base + j] = run; cursor[base + j] = run; run += vals[j]; }
  }
  if (tid == 1023) offsets[NN] = wsum[15];
}

__global__ __launch_bounds__(256) void scatter_kernel(const int* __restrict__ ei,
                                                      int* __restrict__ cursor,
                                                      int* __restrict__ srcs) {
  int e = blockIdx.x * blockDim.x + threadIdx.x;
  if (e >= ET) return;
  int s, d;
  if (e < EE) { s = ei[e]; d = ei[EE + e]; } else { s = d = e - EE; }
  int pos = atomicAdd(&cursor[d], 1);
  srcs[pos] = s;
}

// ---------------- bf16 MFMA GEMM (closed after R8/R12 nulls; ring-3, XCD swizzle) ----------------
__global__ __launch_bounds__(512, 6) void gemm_mfma(const unsigned short* __restrict__ A,
                                                    const unsigned short* __restrict__ Bt,
                                                    unsigned short* __restrict__ xlb,
                                                    float* __restrict__ xrf,
                                                    int M, int K) {
  __shared__ unsigned short As[3][128 * 32];  // 3 x 8 KB
  __shared__ unsigned short Bs[3][128 * 32];  // 3 x 8 KB
  const int tid = threadIdx.x;
  const int wave = tid >> 6;
  const int lane = tid & 63;
  const int am = lane & 15;
  const int aq = lane >> 4;
  const int wr = (wave >> 2) * 64;   // 0 / 64
  const int wc = (wave & 3) * 32;    // 0 / 32 / 64 / 96

  // bijective XCD swizzle (ERRATA #11 formula)
  const int nwg = gridDim.x;         // (M/128)*4
  const int orig = blockIdx.x;
  const int q = nwg >> 3, r = nwg & 7;
  const int xcd = orig & 7, ii = orig >> 3;
  const int wgid = (xcd < r ? xcd * (q + 1) : r * (q + 1) + (xcd - r) * q) + ii;
  const int row0 = (wgid >> 2) * 128;
  const int col0 = (wgid & 3) * 128;

  const int r_ = tid >> 2;           // 0..127
  const int ks = (tid & 3) * 8;
  const size_t aoff = (size_t)(row0 + r_) * K + ks;
  const size_t boff = (size_t)(col0 + r_) * K + ks;

  const int nk = K >> 5;

#define STAGE(tt, bb)                                                    \
  do {                                                                   \
    gld_lds16(A + aoff + (size_t)(tt) * 32, &As[bb][wave * 512]);        \
    gld_lds16(Bt + boff + (size_t)(tt) * 32, &Bs[bb][wave * 512]);       \
  } while (0)

  f32x4 acc[4][2] = {};

  STAGE(0, 0);
  STAGE(1, 1);

  int cur = 0;
  int sb = 2;
  for (int t = 0; t < nk; ++t) {
    if (t + 1 < nk) {
      asm volatile("s_waitcnt vmcnt(2)" ::: "memory");
    } else {
      asm volatile("s_waitcnt vmcnt(0)" ::: "memory");
    }
    __builtin_amdgcn_s_barrier();
    __builtin_amdgcn_sched_barrier(0);

    if (t + 2 < nk) STAGE(t + 2, sb);

    bf16x8 af[4], bfr[2];
#pragma unroll
    for (int i = 0; i < 4; ++i)
      af[i] = *reinterpret_cast<const bf16x8*>(&As[cur][(wr + i * 16 + am) * 32 + aq * 8]);
#pragma unroll
    for (int j = 0; j < 2; ++j)
      bfr[j] = *reinterpret_cast<const bf16x8*>(&Bs[cur][(wc + j * 16 + am) * 32 + aq * 8]);
#pragma unroll
    for (int i = 0; i < 4; ++i)
#pragma unroll
      for (int j = 0; j < 2; ++j)
        acc[i][j] = __builtin_amdgcn_mfma_f32_16x16x32_bf16(af[i], bfr[j], acc[i][j], 0, 0, 0);

    cur = (cur == 2) ? 0 : cur + 1;
    sb = (sb == 2) ? 0 : sb + 1;
  }
#undef STAGE

  // epilogue: D col = lane&15, row = (lane>>4)*4 + reg
#pragma unroll
  for (int i = 0; i < 4; ++i) {
#pragma unroll
    for (int j = 0; j < 2; ++j) {
      int gcol = col0 + wc + j * 16 + am;
#pragma unroll
      for (int rr = 0; rr < 4; ++rr) {
        int grow = row0 + wr + i * 16 + aq * 4 + rr;
        if (grow < M) {
          float v = acc[i][j][rr];
          if (gcol < 256) xlb[(size_t)grow * 256 + gcol] = f2b(v);
          else            xrf[(size_t)grow * 256 + (gcol - 256)] = v;
        }
      }
    }
  }
}

// ---------------- GATv2 layer: wave/node, no-max softmax, 4-edge unroll, BN+ELU epilogue.
// Fused-lin2 mode (Wl2 != nullptr): project z (fp32) onto Wl2/Wr2 -> xl2/xr2, SKIP hb store
// (hb's only consumer was lin2; saves 10MB store + 10MB load + one launch).
__global__ __launch_bounds__(256) void gat_layer(const unsigned short* __restrict__ xlb,
                                                 const float* __restrict__ xrf,
                                                 const float* __restrict__ att,
                                                 const float* __restrict__ bias,
                                                 const float* __restrict__ gam,
                                                 const float* __restrict__ bet,
                                                 const float* __restrict__ mean,
                                                 const float* __restrict__ var,
                                                 const int* __restrict__ offsets,
                                                 const int* __restrict__ srcs,
                                                 unsigned short* __restrict__ hb,
                                                 const float* __restrict__ Wl2,
                                                 const float* __restrict__ Wr2,
                                                 float* __restrict__ xl2,
                                                 float* __restrict__ xr2) {
  const int wave = threadIdx.x >> 6;
  const int lane = threadIdx.x & 63;
  const int node = blockIdx.x * 4 + wave;
  if (node >= NN) return;

  const float4 xr4 = ld4(&xrf[(size_t)node * HC + lane * 4]);
  const float4 a4 = ld4(&att[lane * 4]);
  const int beg = offsets[node];
  const int end = offsets[node + 1];

  float lA = 0.f, lB = 0.f;
  float4 OA = make_float4(0.f, 0.f, 0.f, 0.f);
  float4 OB = make_float4(0.f, 0.f, 0.f, 0.f);

  int i = beg;
  for (; i + 3 < end; i += 4) {
    int s0 = srcs[i], s1 = srcs[i + 1], s2 = srcs[i + 2], s3 = srcs[i + 3];
    ushort4 u0 = *reinterpret_cast<const ushort4*>(&xlb[(size_t)s0 * HC + lane * 4]);
    ushort4 u1 = *reinterpret_cast<const ushort4*>(&xlb[(size_t)s1 * HC + lane * 4]);
    ushort4 u2 = *reinterpret_cast<const ushort4*>(&xlb[(size_t)s2 * HC + lane * 4]);
    ushort4 u3 = *reinterpret_cast<const ushort4*>(&xlb[(size_t)s3 * HC + lane * 4]);
    float4 x0 = make_float4(b2f(u0.x), b2f(u0.y), b2f(u0.z), b2f(u0.w));
    float4 x1 = make_float4(b2f(u1.x), b2f(u1.y), b2f(u1.z), b2f(u1.w));
    float4 x2 = make_float4(b2f(u2.x), b2f(u2.y), b2f(u2.z), b2f(u2.w));
    float4 x3 = make_float4(b2f(u3.x), b2f(u3.y), b2f(u3.z), b2f(u3.w));
    float e0 = lrelu(x0.x + xr4.x) * a4.x + lrelu(x0.y + xr4.y) * a4.y +
               lrelu(x0.z + xr4.z) * a4.z + lrelu(x0.w + xr4.w) * a4.w;
    float e1 = lrelu(x1.x + xr4.x) * a4.x + lrelu(x1.y + xr4.y) * a4.y +
               lrelu(x1.z + xr4.z) * a4.z + lrelu(x1.w + xr4.w) * a4.w;
    float e2 = lrelu(x2.x + xr4.x) * a4.x + lrelu(x2.y + xr4.y) * a4.y +
               lrelu(x2.z + xr4.z) * a4.z + lrelu(x2.w + xr4.w) * a4.w;
    float e3 = lrelu(x3.x + xr4.x) * a4.x + lrelu(x3.y + xr4.y) * a4.y +
               lrelu(x3.z + xr4.z) * a4.z + lrelu(x3.w + xr4.w) * a4.w;
#pragma unroll
    for (int off = 1; off < 16; off <<= 1) {
      e0 += __shfl_xor(e0, off);
      e1 += __shfl_xor(e1, off);
      e2 += __shfl_xor(e2, off);
      e3 += __shfl_xor(e3, off);
    }
    float p0 = __expf(e0), p1 = __expf(e1), p2 = __expf(e2), p3 = __expf(e3);
    lA += p0; lB += p1; lA += p2; lB += p3;
    OA.x += p0 * x0.x; OA.y += p0 * x0.y; OA.z += p0 * x0.z; OA.w += p0 * x0.w;
    OB.x += p1 * x1.x; OB.y += p1 * x1.y; OB.z += p1 * x1.z; OB.w += p1 * x1.w;
    OA.x += p2 * x2.x; OA.y += p2 * x2.y; OA.z += p2 * x2.z; OA.w += p2 * x2.w;
    OB.x += p3 * x3.x; OB.y += p3 * x3.y; OB.z += p3 * x3.z; OB.w += p3 * x3.w;
  }
  for (; i < end; ++i) {
    int s = srcs[i];
    ushort4 u = *reinterpret_cast<const ushort4*>(&xlb[(size_t)s * HC + lane * 4]);
    float4 x0 = make_float4(b2f(u.x), b2f(u.y), b2f(u.z), b2f(u.w));
    float e = lrelu(x0.x + xr4.x) * a4.x + lrelu(x0.y + xr4.y) * a4.y +
              lrelu(x0.z + xr4.z) * a4.z + lrelu(x0.w + xr4.w) * a4.w;
#pragma unroll
    for (int off = 1; off < 16; off <<= 1) e += __shfl_xor(e, off);
    float p = __expf(e);
    lA += p;
    OA.x += p * x0.x; OA.y += p * x0.y; OA.z += p * x0.z; OA.w += p * x0.w;
  }
  float inv = 1.f / (lA + lB);
  float4 O = make_float4(OA.x + OB.x, OA.y + OB.y, OA.z + OB.z, OA.w + OB.w);

  float4 b4 = ld4(&bias[lane * 4]);
  float4 g4 = ld4(&gam[lane * 4]);
  float4 e4 = ld4(&bet[lane * 4]);
  float4 m4 = ld4(&mean[lane * 4]);
  float4 v4 = ld4(&var[lane * 4]);
  float y0 = O.x * inv + b4.x, y1 = O.y * inv + b4.y;
  float y2 = O.z * inv + b4.z, y3 = O.w * inv + b4.w;
  float z0 = (y0 - m4.x) * (g4.x * rsqrtf(v4.x + EPS_BN)) + e4.x;
  float z1 = (y1 - m4.y) * (g4.y * rsqrtf(v4.y + EPS_BN)) + e4.y;
  float z2 = (y2 - m4.z) * (g4.z * rsqrtf(v4.z + EPS_BN)) + e4.z;
  float z3 = (y3 - m4.w) * (g4.w * rsqrtf(v4.w + EPS_BN)) + e4.w;
  z0 = z0 > 0.f ? z0 : expm1f(z0);
  z1 = z1 > 0.f ? z1 : expm1f(z1);
  z2 = z2 > 0.f ? z2 : expm1f(z2);
  z3 = z3 > 0.f ? z3 : expm1f(z3);

  if (Wl2 != nullptr) {
    // fused lin2: h = z (fp32), project 256 -> 2 twice, wave-reduce, lane0 writes
    float zz[4] = {z0, z1, z2, z3};
    float l0 = 0.f, l1 = 0.f, r0 = 0.f, r1 = 0.f;
#pragma unroll
    for (int j = 0; j < 4; ++j) {
      int row = lane * 4 + j;
      l0 += zz[j] * Wl2[row * 2 + 0];
      l1 += zz[j] * Wl2[row * 2 + 1];
      r0 += zz[j] * Wr2[row * 2 + 0];
      r1 += zz[j] * Wr2[row * 2 + 1];
    }
#pragma unroll
    for (int off = 1; off < 64; off <<= 1) {
      l0 += __shfl_xor(l0, off);
      l1 += __shfl_xor(l1, off);
      r0 += __shfl_xor(r0, off);
      r1 += __shfl_xor(r1, off);
    }
    if (lane == 0) {
      xl2[node * 2 + 0] = l0; xl2[node * 2 + 1] = l1;
      xr2[node * 2 + 0] = r0; xr2[node * 2 + 1] = r1;
    }
  } else {
    ushort4 r;
    r.x = f2b(z0); r.y = f2b(z1); r.z = f2b(z2); r.w = f2b(z3);
    *reinterpret_cast<ushort4*>(&hb[(size_t)node * HC + lane * 4]) = r;
  }
}

// ---------------- layer 2 attention + log_softmax (wave per node, lane per edge, no-max) ----------------
__global__ __launch_bounds__(256) void gat2_out_kernel(const float* __restrict__ xl2,
                                                       const float* __restrict__ xr2,
                                                       const float* __restrict__ att2,
                                                       const float* __restrict__ b2,
                                                       const int* __restrict__ offsets,
                                                       const int* __restrict__ srcs,
                                                       float* __restrict__ out) {
  const int wave = threadIdx.x >> 6;
  const int lane = threadIdx.x & 63;
  const int node = blockIdx.x * 4 + wave;
  if (node >= NN) return;
  const float a0 = att2[0], a1 = att2[1];
  const float xr0 = xr2[node * 2 + 0], xr1 = xr2[node * 2 + 1];
  const int beg = offsets[node], end = offsets[node + 1];

  float l = 0.f, o0 = 0.f, o1 = 0.f;
  for (int i = beg + lane; i < end; i += 64) {
    int s = srcs[i];
    float x0 = xl2[s * 2 + 0], x1 = xl2[s * 2 + 1];
    float e = lrelu(x0 + xr0) * a0 + lrelu(x1 + xr1) * a1;
    float p = __expf(e);
    l += p;
    o0 += p * x0;
    o1 += p * x1;
  }
#pragma unroll
  for (int off = 1; off < 64; off <<= 1) {
    l += __shfl_xor(l, off);
    o0 += __shfl_xor(o0, off);
    o1 += __shfl_xor(o1, off);
  }
  if (lane == 0) {
    float inv = 1.f / l;
    float t0 = o0 * inv + b2[0];
    float t1 = o1 * inv + b2[1];
    float mx = fmaxf(t0, t1);
    float ls = mx + logf(__expf(t0 - mx) + __expf(t1 - mx));
    out[node * 2 + 0] = t0 - ls;
    out[node * 2 + 1] = t1 - ls;
  }
}

extern "C" void kernel_launch(void* const* d_in, const int* in_sizes, int n_in,
                              void* d_out, int out_size, void* d_ws, size_t ws_size,
                              hipStream_t stream) {
  const float* x    = (const float*)d_in[0];
  const int*   ei   = (const int*)d_in[1];
  const float* Wl0  = (const float*)d_in[2];
  const float* Wr0  = (const float*)d_in[3];
  const float* att0 = (const float*)d_in[4];
  const float* b0   = (const float*)d_in[5];
  const float* g0   = (const float*)d_in[6];
  const float* be0  = (const float*)d_in[7];
  const float* m0   = (const float*)d_in[8];
  const float* v0   = (const float*)d_in[9];
  const float* Wl1  = (const float*)d_in[10];
  const float* Wr1  = (const float*)d_in[11];
  const float* att1 = (const float*)d_in[12];
  const float* b1   = (const float*)d_in[13];
  const float* g1   = (const float*)d_in[14];
  const float* be1  = (const float*)d_in[15];
  const float* m1   = (const float*)d_in[16];
  const float* v1   = (const float*)d_in[17];
  const float* Wl2  = (const float*)d_in[18];
  const float* Wr2  = (const float*)d_in[19];
  const float* att2 = (const float*)d_in[20];
  const float* b2   = (const float*)d_in[21];

  // workspace layout (~64.2 MB)
  float* xrf = (float*)d_ws;                                   // NN*256 fp32
  unsigned short* xlb = (unsigned short*)(xrf + (size_t)NN * 256);  // NN*256 bf16
  unsigned short* hb  = xlb + (size_t)NN * 256;                // MP*256 bf16
  unsigned short* xb  = hb + (size_t)MP * 256;                 // MP*512 bf16
  unsigned short* Wf0 = xb + (size_t)MP * 512;                 // 512*512 bf16
  unsigned short* Wf1 = Wf0 + 512 * 512;                       // 512*256 bf16
  float* xl2 = (float*)(Wf1 + 512 * 256);                      // 2*NN
  float* xr2 = xl2 + 2 * NN;                                   // 2*NN
  int* offsets = (int*)(xr2 + 2 * NN);                         // NN+1
  int* cursor  = offsets + (NN + 1);                           // NN
  int* srcs    = cursor + NN;                                  // ET

  // --- fused prep (convert_x | hist | convert_w0 | convert_w1) + CSR build ---
  hipMemsetAsync(cursor, 0, NN * sizeof(int), stream);
  prep_kernel<<<CXB + HB + W0B + W1B, 256, 0, stream>>>(x, xb, ei, cursor,
                                                        Wl0, Wr0, Wf0, Wl1, Wr1, Wf1);
  scan_kernel<<<1, 1024, 0, stream>>>(cursor, offsets);
  scatter_kernel<<<(ET + 255) / 256, 256, 0, stream>>>(ei, cursor, srcs);

  const int gemm_blocks = (MP / 128) * 4;  // 628, 1D grid (swizzled in-kernel)
  // --- layer 0 ---
  gemm_mfma<<<gemm_blocks, 512, 0, stream>>>(xb, Wf0, xlb, xrf, NN, 512);
  gat_layer<<<NN / 4, 256, 0, stream>>>(xlb, xrf, att0, b0, g0, be0, m0, v0, offsets, srcs, hb,
                                        nullptr, nullptr, nullptr, nullptr);
  // --- layer 1 (lin2 fused into epilogue; hb not written) ---
  gemm_mfma<<<gemm_blocks, 512, 0, stream>>>(hb, Wf1, xlb, xrf, NN, 256);
  gat_layer<<<NN / 4, 256, 0, stream>>>(xlb, xrf, att1, b1, g1, be1, m1, v1, offsets, srcs, hb,
                                        Wl2, Wr2, xl2, xr2);
  // --- layer 2 ---
  gat2_out_kernel<<<NN / 4, 256, 0, stream>>>(xl2, xr2, att2, b2, offsets, srcs, (float*)d_out);
}

// Round 19
// 279.054 us; speedup vs baseline: 1.2934x; 1.0045x over previous
//
#include <hip/hip_runtime.h>
#include <math.h>

#define NN 20000
#define MP 20096          // NN padded to multiple of 128 for MFMA GEMM A-reads
#define EE 320000
#define ET (EE + NN)
#define HC 256
#define EPS_BN 1e-5f

typedef __bf16 bf16x8 __attribute__((ext_vector_type(8)));
typedef float f32x4 __attribute__((ext_vector_type(4)));

__device__ __forceinline__ float4 ld4(const float* p) { return *reinterpret_cast<const float4*>(p); }
__device__ __forceinline__ float lrelu(float x) { return fmaxf(x, 0.f) + 0.2f * fminf(x, 0.f); }

// fp32 -> bf16 (RNE), raw ushort storage
__device__ __forceinline__ unsigned short f2b(float f) {
  unsigned int u = __float_as_uint(f);
  u = (u + 0x7fffu + ((u >> 16) & 1u)) >> 16;
  return (unsigned short)u;
}
__device__ __forceinline__ float b2f(unsigned short u) {
  return __uint_as_float(((unsigned int)u) << 16);
}

// async global->LDS, 16B per lane; LDS dest = wave-uniform base + lane*16
__device__ __forceinline__ void gld_lds16(const void* g, void* l) {
  __builtin_amdgcn_global_load_lds(
      (const __attribute__((address_space(1))) unsigned int*)g,
      (__attribute__((address_space(3))) unsigned int*)(unsigned int)(unsigned long long)l,
      16, 0, 0);
}

// ---------------- fused prep: convert_x | hist | convert_w0 | convert_w1 ----------------
// (R16 lesson: hist must stay massively parallel — single-block LDS hist was 120-160us)
#define CXB 5000                  // NN*512/8/256 (8 floats per thread)
#define HB  ((ET + 255) / 256)    // 1329
#define W0B 1024                  // 512*512/256
#define W1B 512                   // 512*256/256

__device__ __forceinline__ void conv_w_body(int idx, int K, const float* Wl, const float* Wr,
                                            unsigned short* Wf) {
  int n = idx / K, k = idx - n * K;
  float v = (n < 256) ? Wl[(size_t)k * 256 + n] : Wr[(size_t)k * 256 + (n - 256)];
  Wf[idx] = f2b(v);
}

__global__ __launch_bounds__(256) void prep_kernel(const float* __restrict__ x,
                                                   unsigned short* __restrict__ xb,
                                                   const int* __restrict__ ei,
                                                   int* __restrict__ counts,
                                                   const float* __restrict__ Wl0,
                                                   const float* __restrict__ Wr0,
                                                   unsigned short* __restrict__ Wf0,
                                                   const float* __restrict__ Wl1,
                                                   const float* __restrict__ Wr1,
                                                   unsigned short* __restrict__ Wf1) {
  const int b = blockIdx.x;
  if (b < CXB) {
    // convert_x: NN*512 floats -> bf16, 8/thread (exactly covers 10,240,000)
    int i = (b * 256 + threadIdx.x) * 8;
    float4 v0 = ld4(&x[i]);
    float4 v1 = ld4(&x[i + 4]);
    ushort4 o0, o1;
    o0.x = f2b(v0.x); o0.y = f2b(v0.y); o0.z = f2b(v0.z); o0.w = f2b(v0.w);
    o1.x = f2b(v1.x); o1.y = f2b(v1.y); o1.z = f2b(v1.z); o1.w = f2b(v1.w);
    *reinterpret_cast<ushort4*>(&xb[i]) = o0;
    *reinterpret_cast<ushort4*>(&xb[i + 4]) = o1;
  } else if (b < CXB + HB) {
    int e = (b - CXB) * 256 + threadIdx.x;
    if (e < ET) {
      int d = (e < EE) ? ei[EE + e] : (e - EE);
      atomicAdd(&counts[d], 1);
    }
  } else if (b < CXB + HB + W0B) {
    conv_w_body((b - CXB - HB) * 256 + threadIdx.x, 512, Wl0, Wr0, Wf0);
  } else {
    conv_w_body((b - CXB - HB - W0B) * 256 + threadIdx.x, 256, Wl1, Wr1, Wf1);
  }
}

// ---------------- CSR build: scan + scatter ----------------
// single-block scan: 1024 threads x 20 ints each, shfl-based, 2 barriers
__global__ __launch_bounds__(1024) void scan_kernel(int* __restrict__ cursor,
                                                    int* __restrict__ offsets) {
  __shared__ int wsum[16];
  const int tid = threadIdx.x;
  const int lane = tid & 63, wv = tid >> 6;
  const int base = tid * 20;
  int vals[20];
  int s = 0;
  if (tid < 1000) {
#pragma unroll
    for (int j = 0; j < 20; ++j) { vals[j] = cursor[base + j]; s += vals[j]; }
  }
  int ssum = s;  // inclusive wave scan
#pragma unroll
  for (int off = 1; off < 64; off <<= 1) {
    int t = __shfl_up(ssum, off);
    if (lane >= off) ssum += t;
  }
  if (lane == 63) wsum[wv] = ssum;
  __syncthreads();
  if (wv == 0) {
    int w = (lane < 16) ? wsum[lane] : 0;
#pragma unroll
    for (int off = 1; off < 16; off <<= 1) {
      int t = __shfl_up(w, off);
      if (lane >= off) w += t;
    }
    if (lane < 16) wsum[lane] = w;
  }
  __syncthreads();
  int excl = ssum - s + (wv > 0 ? wsum[wv - 1] : 0);
  if (tid < 1000) {
    int run = excl;
#pragma unroll
    for (int j = 0; j < 20; ++j) { offsets[base + j] = run; cursor[base + j] = run; run += vals[j]; }
  }
  if (tid == 1023) offsets[NN] = wsum[15];
}

__global__ __launch_bounds__(256) void scatter_kernel(const int* __restrict__ ei,
                                                      int* __restrict__ cursor,
                                                      int* __restrict__ srcs) {
  int e = blockIdx.x * blockDim.x + threadIdx.x;
  if (e >= ET) return;
  int s, d;
  if (e < EE) { s = ei[e]; d = ei[EE + e]; } else { s = d = e - EE; }
  int pos = atomicAdd(&cursor[d], 1);
  srcs[pos] = s;
}

// ---------------- bf16 MFMA GEMM (closed after R8/R12 nulls; ring-3, XCD swizzle) ----------------
__global__ __launch_bounds__(512, 6) void gemm_mfma(const unsigned short* __restrict__ A,
                                                    const unsigned short* __restrict__ Bt,
                                                    unsigned short* __restrict__ xlb,
                                                    float* __restrict__ xrf,
                                                    int M, int K) {
  __shared__ unsigned short As[3][128 * 32];  // 3 x 8 KB
  __shared__ unsigned short Bs[3][128 * 32];  // 3 x 8 KB
  const int tid = threadIdx.x;
  const int wave = tid >> 6;
  const int lane = tid & 63;
  const int am = lane & 15;
  const int aq = lane >> 4;
  const int wr = (wave >> 2) * 64;   // 0 / 64
  const int wc = (wave & 3) * 32;    // 0 / 32 / 64 / 96

  // bijective XCD swizzle (ERRATA #11 formula)
  const int nwg = gridDim.x;         // (M/128)*4
  const int orig = blockIdx.x;
  const int q = nwg >> 3, r = nwg & 7;
  const int xcd = orig & 7, ii = orig >> 3;
  const int wgid = (xcd < r ? xcd * (q + 1) : r * (q + 1) + (xcd - r) * q) + ii;
  const int row0 = (wgid >> 2) * 128;
  const int col0 = (wgid & 3) * 128;

  const int r_ = tid >> 2;           // 0..127
  const int ks = (tid & 3) * 8;
  const size_t aoff = (size_t)(row0 + r_) * K + ks;
  const size_t boff = (size_t)(col0 + r_) * K + ks;

  const int nk = K >> 5;

#define STAGE(tt, bb)                                                    \
  do {                                                                   \
    gld_lds16(A + aoff + (size_t)(tt) * 32, &As[bb][wave * 512]);        \
    gld_lds16(Bt + boff + (size_t)(tt) * 32, &Bs[bb][wave * 512]);       \
  } while (0)

  f32x4 acc[4][2] = {};

  STAGE(0, 0);
  STAGE(1, 1);

  int cur = 0;
  int sb = 2;
  for (int t = 0; t < nk; ++t) {
    if (t + 1 < nk) {
      asm volatile("s_waitcnt vmcnt(2)" ::: "memory");
    } else {
      asm volatile("s_waitcnt vmcnt(0)" ::: "memory");
    }
    __builtin_amdgcn_s_barrier();
    __builtin_amdgcn_sched_barrier(0);

    if (t + 2 < nk) STAGE(t + 2, sb);

    bf16x8 af[4], bfr[2];
#pragma unroll
    for (int i = 0; i < 4; ++i)
      af[i] = *reinterpret_cast<const bf16x8*>(&As[cur][(wr + i * 16 + am) * 32 + aq * 8]);
#pragma unroll
    for (int j = 0; j < 2; ++j)
      bfr[j] = *reinterpret_cast<const bf16x8*>(&Bs[cur][(wc + j * 16 + am) * 32 + aq * 8]);
#pragma unroll
    for (int i = 0; i < 4; ++i)
#pragma unroll
      for (int j = 0; j < 2; ++j)
        acc[i][j] = __builtin_amdgcn_mfma_f32_16x16x32_bf16(af[i], bfr[j], acc[i][j], 0, 0, 0);

    cur = (cur == 2) ? 0 : cur + 1;
    sb = (sb == 2) ? 0 : sb + 1;
  }
#undef STAGE

  // epilogue: D col = lane&15, row = (lane>>4)*4 + reg
#pragma unroll
  for (int i = 0; i < 4; ++i) {
#pragma unroll
    for (int j = 0; j < 2; ++j) {
      int gcol = col0 + wc + j * 16 + am;
#pragma unroll
      for (int rr = 0; rr < 4; ++rr) {
        int grow = row0 + wr + i * 16 + aq * 4 + rr;
        if (grow < M) {
          float v = acc[i][j][rr];
          if (gcol < 256) xlb[(size_t)grow * 256 + gcol] = f2b(v);
          else            xrf[(size_t)grow * 256 + (gcol - 256)] = v;
        }
      }
    }
  }
}

// ---------------- GATv2 layer: wave/node, no-max softmax, 4-edge unroll, BN+ELU epilogue.
// VALU-bound (R18: VALUBusy 66.6%, hbm 21%) -> lrelu algebra: lrelu(x)*a == (0.6a)*x + (0.4a)*|x|
// (exact; |x| folds into a free VOP3 input modifier) cuts per-channel chain 5 ops -> 3.
// Fused-lin2 mode (Wl2 != nullptr): project z (fp32) onto Wl2/Wr2 -> xl2/xr2, SKIP hb store.
__global__ __launch_bounds__(256) void gat_layer(const unsigned short* __restrict__ xlb,
                                                 const float* __restrict__ xrf,
                                                 const float* __restrict__ att,
                                                 const float* __restrict__ bias,
                                                 const float* __restrict__ gam,
                                                 const float* __restrict__ bet,
                                                 const float* __restrict__ mean,
                                                 const float* __restrict__ var,
                                                 const int* __restrict__ offsets,
                                                 const int* __restrict__ srcs,
                                                 unsigned short* __restrict__ hb,
                                                 const float* __restrict__ Wl2,
                                                 const float* __restrict__ Wr2,
                                                 float* __restrict__ xl2,
                                                 float* __restrict__ xr2) {
  const int wave = threadIdx.x >> 6;
  const int lane = threadIdx.x & 63;
  const int node = blockIdx.x * 4 + wave;
  if (node >= NN) return;

  const float4 xr4 = ld4(&xrf[(size_t)node * HC + lane * 4]);
  const float4 a4 = ld4(&att[lane * 4]);
  // lrelu(x)*a = a6*x + a4*|x| with a6=0.6a, a4=0.4a (exact: x>0 -> a*x; x<0 -> 0.2a*x)
  const float4 a6 = make_float4(0.6f * a4.x, 0.6f * a4.y, 0.6f * a4.z, 0.6f * a4.w);
  const float4 aA = make_float4(0.4f * a4.x, 0.4f * a4.y, 0.4f * a4.z, 0.4f * a4.w);
  const int beg = offsets[node];
  const int end = offsets[node + 1];

  float lA = 0.f, lB = 0.f;
  float4 OA = make_float4(0.f, 0.f, 0.f, 0.f);
  float4 OB = make_float4(0.f, 0.f, 0.f, 0.f);

#define EDGE_E(xv, ev)                                                     \
  do {                                                                     \
    float t0 = xv.x + xr4.x, t1 = xv.y + xr4.y;                            \
    float t2 = xv.z + xr4.z, t3 = xv.w + xr4.w;                            \
    ev = a6.x * t0 + aA.x * fabsf(t0) + a6.y * t1 + aA.y * fabsf(t1) +     \
         a6.z * t2 + aA.z * fabsf(t2) + a6.w * t3 + aA.w * fabsf(t3);      \
  } while (0)

  int i = beg;
  for (; i + 3 < end; i += 4) {
    int s0 = srcs[i], s1 = srcs[i + 1], s2 = srcs[i + 2], s3 = srcs[i + 3];
    ushort4 u0 = *reinterpret_cast<const ushort4*>(&xlb[(size_t)s0 * HC + lane * 4]);
    ushort4 u1 = *reinterpret_cast<const ushort4*>(&xlb[(size_t)s1 * HC + lane * 4]);
    ushort4 u2 = *reinterpret_cast<const ushort4*>(&xlb[(size_t)s2 * HC + lane * 4]);
    ushort4 u3 = *reinterpret_cast<const ushort4*>(&xlb[(size_t)s3 * HC + lane * 4]);
    float4 x0 = make_float4(b2f(u0.x), b2f(u0.y), b2f(u0.z), b2f(u0.w));
    float4 x1 = make_float4(b2f(u1.x), b2f(u1.y), b2f(u1.z), b2f(u1.w));
    float4 x2 = make_float4(b2f(u2.x), b2f(u2.y), b2f(u2.z), b2f(u2.w));
    float4 x3 = make_float4(b2f(u3.x), b2f(u3.y), b2f(u3.z), b2f(u3.w));
    float e0, e1, e2, e3;
    EDGE_E(x0, e0);
    EDGE_E(x1, e1);
    EDGE_E(x2, e2);
    EDGE_E(x3, e3);
#pragma unroll
    for (int off = 1; off < 16; off <<= 1) {
      e0 += __shfl_xor(e0, off);
      e1 += __shfl_xor(e1, off);
      e2 += __shfl_xor(e2, off);
      e3 += __shfl_xor(e3, off);
    }
    float p0 = __expf(e0), p1 = __expf(e1), p2 = __expf(e2), p3 = __expf(e3);
    lA += p0; lB += p1; lA += p2; lB += p3;
    OA.x += p0 * x0.x; OA.y += p0 * x0.y; OA.z += p0 * x0.z; OA.w += p0 * x0.w;
    OB.x += p1 * x1.x; OB.y += p1 * x1.y; OB.z += p1 * x1.z; OB.w += p1 * x1.w;
    OA.x += p2 * x2.x; OA.y += p2 * x2.y; OA.z += p2 * x2.z; OA.w += p2 * x2.w;
    OB.x += p3 * x3.x; OB.y += p3 * x3.y; OB.z += p3 * x3.z; OB.w += p3 * x3.w;
  }
  for (; i < end; ++i) {
    int s = srcs[i];
    ushort4 u = *reinterpret_cast<const ushort4*>(&xlb[(size_t)s * HC + lane * 4]);
    float4 x0 = make_float4(b2f(u.x), b2f(u.y), b2f(u.z), b2f(u.w));
    float e;
    EDGE_E(x0, e);
#pragma unroll
    for (int off = 1; off < 16; off <<= 1) e += __shfl_xor(e, off);
    float p = __expf(e);
    lA += p;
    OA.x += p * x0.x; OA.y += p * x0.y; OA.z += p * x0.z; OA.w += p * x0.w;
  }
#undef EDGE_E
  float inv = 1.f / (lA + lB);
  float4 O = make_float4(OA.x + OB.x, OA.y + OB.y, OA.z + OB.z, OA.w + OB.w);

  float4 b4 = ld4(&bias[lane * 4]);
  float4 g4 = ld4(&gam[lane * 4]);
  float4 e4 = ld4(&bet[lane * 4]);
  float4 m4 = ld4(&mean[lane * 4]);
  float4 v4 = ld4(&var[lane * 4]);
  float y0 = O.x * inv + b4.x, y1 = O.y * inv + b4.y;
  float y2 = O.z * inv + b4.z, y3 = O.w * inv + b4.w;
  float z0 = (y0 - m4.x) * (g4.x * rsqrtf(v4.x + EPS_BN)) + e4.x;
  float z1 = (y1 - m4.y) * (g4.y * rsqrtf(v4.y + EPS_BN)) + e4.y;
  float z2 = (y2 - m4.z) * (g4.z * rsqrtf(v4.z + EPS_BN)) + e4.z;
  float z3 = (y3 - m4.w) * (g4.w * rsqrtf(v4.w + EPS_BN)) + e4.w;
  z0 = z0 > 0.f ? z0 : expm1f(z0);
  z1 = z1 > 0.f ? z1 : expm1f(z1);
  z2 = z2 > 0.f ? z2 : expm1f(z2);
  z3 = z3 > 0.f ? z3 : expm1f(z3);

  if (Wl2 != nullptr) {
    // fused lin2: h = z (fp32), project 256 -> 2 twice, wave-reduce, lane0 writes
    float zz[4] = {z0, z1, z2, z3};
    float l0 = 0.f, l1 = 0.f, r0 = 0.f, r1 = 0.f;
#pragma unroll
    for (int j = 0; j < 4; ++j) {
      int row = lane * 4 + j;
      l0 += zz[j] * Wl2[row * 2 + 0];
      l1 += zz[j] * Wl2[row * 2 + 1];
      r0 += zz[j] * Wr2[row * 2 + 0];
      r1 += zz[j] * Wr2[row * 2 + 1];
    }
#pragma unroll
    for (int off = 1; off < 64; off <<= 1) {
      l0 += __shfl_xor(l0, off);
      l1 += __shfl_xor(l1, off);
      r0 += __shfl_xor(r0, off);
      r1 += __shfl_xor(r1, off);
    }
    if (lane == 0) {
      xl2[node * 2 + 0] = l0; xl2[node * 2 + 1] = l1;
      xr2[node * 2 + 0] = r0; xr2[node * 2 + 1] = r1;
    }
  } else {
    ushort4 r;
    r.x = f2b(z0); r.y = f2b(z1); r.z = f2b(z2); r.w = f2b(z3);
    *reinterpret_cast<ushort4*>(&hb[(size_t)node * HC + lane * 4]) = r;
  }
}

// ---------------- layer 2 attention + log_softmax (wave per node, lane per edge, no-max) ----------------
__global__ __launch_bounds__(256) void gat2_out_kernel(const float* __restrict__ xl2,
                                                       const float* __restrict__ xr2,
                                                       const float* __restrict__ att2,
                                                       const float* __restrict__ b2,
                                                       const int* __restrict__ offsets,
                                                       const int* __restrict__ srcs,
                                                       float* __restrict__ out) {
  const int wave = threadIdx.x >> 6;
  const int lane = threadIdx.x & 63;
  const int node = blockIdx.x * 4 + wave;
  if (node >= NN) return;
  const float a0 = att2[0], a1 = att2[1];
  const float xr0 = xr2[node * 2 + 0], xr1 = xr2[node * 2 + 1];
  const int beg = offsets[node], end = offsets[node + 1];

  float l = 0.f, o0 = 0.f, o1 = 0.f;
  for (int i = beg + lane; i < end; i += 64) {
    int s = srcs[i];
    float x0 = xl2[s * 2 + 0], x1 = xl2[s * 2 + 1];
    float e = lrelu(x0 + xr0) * a0 + lrelu(x1 + xr1) * a1;
    float p = __expf(e);
    l += p;
    o0 += p * x0;
    o1 += p * x1;
  }
#pragma unroll
  for (int off = 1; off < 64; off <<= 1) {
    l += __shfl_xor(l, off);
    o0 += __shfl_xor(o0, off);
    o1 += __shfl_xor(o1, off);
  }
  if (lane == 0) {
    float inv = 1.f / l;
    float t0 = o0 * inv + b2[0];
    float t1 = o1 * inv + b2[1];
    float mx = fmaxf(t0, t1);
    float ls = mx + logf(__expf(t0 - mx) + __expf(t1 - mx));
    out[node * 2 + 0] = t0 - ls;
    out[node * 2 + 1] = t1 - ls;
  }
}

extern "C" void kernel_launch(void* const* d_in, const int* in_sizes, int n_in,
                              void* d_out, int out_size, void* d_ws, size_t ws_size,
                              hipStream_t stream) {
  const float* x    = (const float*)d_in[0];
  const int*   ei   = (const int*)d_in[1];
  const float* Wl0  = (const float*)d_in[2];
  const float* Wr0  = (const float*)d_in[3];
  const float* att0 = (const float*)d_in[4];
  const float* b0   = (const float*)d_in[5];
  const float* g0   = (const float*)d_in[6];
  const float* be0  = (const float*)d_in[7];
  const float* m0   = (const float*)d_in[8];
  const float* v0   = (const float*)d_in[9];
  const float* Wl1  = (const float*)d_in[10];
  const float* Wr1  = (const float*)d_in[11];
  const float* att1 = (const float*)d_in[12];
  const float* b1   = (const float*)d_in[13];
  const float* g1   = (const float*)d_in[14];
  const float* be1  = (const float*)d_in[15];
  const float* m1   = (const float*)d_in[16];
  const float* v1   = (const float*)d_in[17];
  const float* Wl2  = (const float*)d_in[18];
  const float* Wr2  = (const float*)d_in[19];
  const float* att2 = (const float*)d_in[20];
  const float* b2   = (const float*)d_in[21];

  // workspace layout (~64.2 MB)
  float* xrf = (float*)d_ws;                                   // NN*256 fp32
  unsigned short* xlb = (unsigned short*)(xrf + (size_t)NN * 256);  // NN*256 bf16
  unsigned short* hb  = xlb + (size_t)NN * 256;                // MP*256 bf16
  unsigned short* xb  = hb + (size_t)MP * 256;                 // MP*512 bf16
  unsigned short* Wf0 = xb + (size_t)MP * 512;                 // 512*512 bf16
  unsigned short* Wf1 = Wf0 + 512 * 512;                       // 512*256 bf16
  float* xl2 = (float*)(Wf1 + 512 * 256);                      // 2*NN
  float* xr2 = xl2 + 2 * NN;                                   // 2*NN
  int* offsets = (int*)(xr2 + 2 * NN);                         // NN+1
  int* cursor  = offsets + (NN + 1);                           // NN
  int* srcs    = cursor + NN;                                  // ET

  // --- fused prep (convert_x | hist | convert_w0 | convert_w1) + CSR build ---
  hipMemsetAsync(cursor, 0, NN * sizeof(int), stream);
  prep_kernel<<<CXB + HB + W0B + W1B, 256, 0, stream>>>(x, xb, ei, cursor,
                                                        Wl0, Wr0, Wf0, Wl1, Wr1, Wf1);
  scan_kernel<<<1, 1024, 0, stream>>>(cursor, offsets);
  scatter_kernel<<<(ET + 255) / 256, 256, 0, stream>>>(ei, cursor, srcs);

  const int gemm_blocks = (MP / 128) * 4;  // 628, 1D grid (swizzled in-kernel)
  // --- layer 0 ---
  gemm_mfma<<<gemm_blocks, 512, 0, stream>>>(xb, Wf0, xlb, xrf, NN, 512);
  gat_layer<<<NN / 4, 256, 0, stream>>>(xlb, xrf, att0, b0, g0, be0, m0, v0, offsets, srcs, hb,
                                        nullptr, nullptr, nullptr, nullptr);
  // --- layer 1 (lin2 fused into epilogue; hb not written) ---
  gemm_mfma<<<gemm_blocks, 512, 0, stream>>>(hb, Wf1, xlb, xrf, NN, 256);
  gat_layer<<<NN / 4, 256, 0, stream>>>(xlb, xrf, att1, b1, g1, be1, m1, v1, offsets, srcs, hb,
                                        Wl2, Wr2, xl2, xr2);
  // --- layer 2 ---
  gat2_out_kernel<<<NN / 4, 256, 0, stream>>>(xl2, xr2, att2, b2, offsets, srcs, (float*)d_out);
}